// Round 9
// baseline (156.964 us; speedup 1.0000x reference)
//
#include <hip/hip_runtime.h>
#include <hip/hip_bf16.h>

// RNN_73048803770905: fused [B,T,200]x[200,64] projection + 128-step tanh RNN + sigmoid head.
// B=4096, T=128, D_IN=200, H=64. 419 MB x read once; HBM floor ~67us.
// R9: R8 (passing, independent waves, acc-as-C, zero in-loop barriers) with the grid
// FIXED: 1024 blocks at exactly 4 blocks/CU (launch_bounds(256,4), 4 waves/SIMD, one
// generation, no tail). VGPR diet to fit 128: px split pA(ks0-3)/pB(ks4-6), cvt8 inline
// (transient frag), LOADB at chunk start, only pA in flight across the 16-step phase,
// Wout read in epilogue. All numerics/logic identical to R8's verified version.

#define TSEQ 128
#define DIN  200
#define HID  64
#define CT   16
#define NCH  (TSEQ/CT)   // 8

typedef short bf16x8 __attribute__((ext_vector_type(8)));
typedef float f32x4  __attribute__((ext_vector_type(4)));

__device__ __forceinline__ unsigned short f2bf(float f) {
  __hip_bfloat16 h = __float2bfloat16(f);
  return __builtin_bit_cast(unsigned short, h);
}
__device__ __forceinline__ bf16x8 cvt8(f32x4 a, f32x4 b) {
  bf16x8 r;
#pragma unroll
  for (int i = 0; i < 4; ++i) { r[i] = (short)f2bf(a[i]); r[4 + i] = (short)f2bf(b[i]); }
  return r;
}
// tanh(x) = 1 - 2/(1 + 2^(x*2/ln2)); v_exp_f32 handles the extremes.
__device__ __forceinline__ float tanh_fast(float x) {
  float e = exp2f(x * 2.885390081777927f);
  float r = __builtin_amdgcn_rcpf(1.f + e);
  return __builtin_fmaf(-2.f, r, 1.f);
}

__global__ __launch_bounds__(256, 4) void rnn_fused(
    const float* __restrict__ x,   const float* __restrict__ Wih,
    const float* __restrict__ Whh, const float* __restrict__ bih,
    const float* __restrict__ bhh, const float* __restrict__ Wout,
    const float* __restrict__ bout, float* __restrict__ out)
{
  __shared__ unsigned short wihL[28][64][8];   // Wih bf16 frags, shared: 28 KB
  __shared__ unsigned short hb[4][2][80];      // per-wave h double buffer: 1.25 KB

  const int tid  = threadIdx.x;
  const int w    = tid >> 6;
  const int lane = tid & 63;
  const int m    = lane & 15;
  const int g    = lane >> 4;
  const int row  = blockIdx.x * 4 + w;         // 1024 blocks, 1 batch row per wave

  // A-frag loads: lane (g,m) holds x[row][t = 16c + m][k = ks*32 + g*8 + j].
  const float* xl = x + ((size_t)row * TSEQ + m) * DIN;

  f32x4 pA[4][2], pB[3][2];
  auto LOADA = [&](int c) {   // ks 0..3 (32 VGPR) - long-flight batch, lives across steps
    const float* p = xl + (size_t)c * (CT * DIN);
#pragma unroll
    for (int ks = 0; ks < 4; ++ks) {
      const int d = ks * 32 + g * 8;
      pA[ks][0] = *reinterpret_cast<const f32x4*>(p + d);
      pA[ks][1] = *reinterpret_cast<const f32x4*>(p + d + 4);
    }
  };
  auto LOADB = [&](int c) {   // ks 4..6 (24 VGPR) - issued at chunk start, consumed same chunk
    const float* p = xl + (size_t)c * (CT * DIN);
#pragma unroll
    for (int ks = 4; ks < 6; ++ks) {
      const int d = ks * 32 + g * 8;
      pB[ks - 4][0] = *reinterpret_cast<const f32x4*>(p + d);
      pB[ks - 4][1] = *reinterpret_cast<const f32x4*>(p + d + 4);
    }
    pB[2][0] = *reinterpret_cast<const f32x4*>(p + 192);   // tail d=192..199, all lanes
    pB[2][1] = *reinterpret_cast<const f32x4*>(p + 196);   // (zeroed at cvt for g>0)
  };
  LOADA(0);   // chunk 0 ks0-3 in flight during init

  // ---- shared Wih frags: frag f = nt*7+ks; lane = Wih[nt*16+m][ks*32+g*8..+7]
  for (int f = w; f < 28; f += 4) {
    const int nt = f / 7, ks = f % 7;
    const int d  = ks * 32 + g * 8;
    bf16x8 v = (bf16x8)0;
    if (d + 8 <= DIN) {
      const float* wr = Wih + (size_t)(nt * 16 + m) * DIN + d;
      v = cvt8(*reinterpret_cast<const f32x4*>(wr), *reinterpret_cast<const f32x4*>(wr + 4));
    }
    *reinterpret_cast<bf16x8*>(&wihL[f][lane][0]) = v;
  }

  // ---- Whh frags in regs (32 VGPR): B[k][n=h], lane n = nt*16+m, k = hf*32+g*8+j
  bf16x8 whhf[4][2];
#pragma unroll
  for (int nt = 0; nt < 4; ++nt)
#pragma unroll
    for (int hf = 0; hf < 2; ++hf) {
      const float* wr = Whh + (size_t)(nt * 16 + m) * HID + hf * 32 + g * 8;
      whhf[nt][hf] = cvt8(*reinterpret_cast<const f32x4*>(wr),
                          *reinterpret_cast<const f32x4*>(wr + 4));
    }
  float biasv[4];
#pragma unroll
  for (int nt = 0; nt < 4; ++nt) biasv[nt] = bih[nt * 16 + m] + bhh[nt * 16 + m];

  hb[w][0][lane] = 0;   // h_{-1} = 0; t=0 reads buf 1
  hb[w][1][lane] = 0;
  __syncthreads();      // wihL ready; ONLY barrier in the kernel

  float vfin[4] = {0.f, 0.f, 0.f, 0.f};   // final h, valid on g==3 lanes

  for (int c = 0; c < NCH; ++c) {
    LOADB(c);   // ks4-6 of current chunk; latency hides under ks0-3 cvt+MFMA

    // ---- proj: acc = x_tile * Wih^T + bias; 16 D rows = 16 timesteps; acc stays as C
    f32x4 acc[4];
#pragma unroll
    for (int nt = 0; nt < 4; ++nt) acc[nt] = (f32x4)(biasv[nt]);
#pragma unroll
    for (int ks = 0; ks < 4; ++ks) {
      const bf16x8 a = cvt8(pA[ks][0], pA[ks][1]);   // vmcnt wait for pA(c) lands here
#pragma unroll
      for (int nt = 0; nt < 4; ++nt) {
        bf16x8 bv = *reinterpret_cast<const bf16x8*>(&wihL[nt * 7 + ks][lane][0]);
        acc[nt] = __builtin_amdgcn_mfma_f32_16x16x32_bf16(a, bv, acc[nt], 0, 0, 0);
      }
    }
    if (c + 1 < NCH) LOADA(c + 1);   // pA free; in flight across ks4-6 + all 16 steps
#pragma unroll
    for (int ks = 4; ks < 7; ++ks) {
      const bf16x8 a = (ks < 6) ? cvt8(pB[ks - 4][0], pB[ks - 4][1])
                                : ((g == 0) ? cvt8(pB[2][0], pB[2][1]) : (bf16x8)0);
#pragma unroll
      for (int nt = 0; nt < 4; ++nt) {
        bf16x8 bv = *reinterpret_cast<const bf16x8*>(&wihL[nt * 7 + ks][lane][0]);
        acc[nt] = __builtin_amdgcn_mfma_f32_16x16x32_bf16(a, bv, acc[nt], 0, 0, 0);
      }
    }

    // ---- 16 recurrence steps, fully in-wave (R8-verified). A = h_{t-1} broadcast to
    // all 16 rows (uniform conflict-free ds_read); D row s valid at g = s>>2, reg s&3.
#pragma unroll
    for (int s = 0; s < CT; ++s) {
      const int rb = s & 1, pb = rb ^ 1;   // compile-time parity (CT even)
      asm volatile("" ::: "memory");       // fence: no reordering of h LDS ops
      bf16x8 ha0 = *reinterpret_cast<const bf16x8*>(&hb[w][pb][g * 8]);        // k 0..31
      bf16x8 ha1 = *reinterpret_cast<const bf16x8*>(&hb[w][pb][32 + g * 8]);   // k 32..63
      f32x4 racc[4];
#pragma unroll
      for (int nt = 0; nt < 4; ++nt)
        racc[nt] = __builtin_amdgcn_mfma_f32_16x16x32_bf16(ha0, whhf[nt][0], acc[nt], 0, 0, 0);
#pragma unroll
      for (int nt = 0; nt < 4; ++nt)
        racc[nt] = __builtin_amdgcn_mfma_f32_16x16x32_bf16(ha1, whhf[nt][1], racc[nt], 0, 0, 0);
      if (g == (s >> 2)) {                 // the one group holding D row s
#pragma unroll
        for (int nt = 0; nt < 4; ++nt) {
          const float v = tanh_fast(racc[nt][s & 3]);
          hb[w][rb][nt * 16 + m] = f2bf(v);          // 16 lanes x 4 cols = all 64
          if (s == CT - 1) vfin[nt] = v;
        }
      }
      asm volatile("" ::: "memory");
    }
  }

  // ---- epilogue: g==3 lanes hold final h; reduce within the 16-lane group
  float sred = vfin[0] * Wout[m]      + vfin[1] * Wout[16 + m]
             + vfin[2] * Wout[32 + m] + vfin[3] * Wout[48 + m];
  sred += __shfl_xor(sred, 1, 64);
  sred += __shfl_xor(sred, 2, 64);
  sred += __shfl_xor(sred, 4, 64);
  sred += __shfl_xor(sred, 8, 64);
  if (lane == 48)
    out[row] = __builtin_amdgcn_rcpf(1.f + exp2f(-(sred + bout[0]) * 1.4426950408889634f));
}

extern "C" void kernel_launch(void* const* d_in, const int* in_sizes, int n_in,
                              void* d_out, int out_size, void* d_ws, size_t ws_size,
                              hipStream_t stream) {
  const float* x    = (const float*)d_in[0];
  const float* Wih  = (const float*)d_in[1];
  const float* Whh  = (const float*)d_in[2];
  const float* bih  = (const float*)d_in[3];
  const float* bhh  = (const float*)d_in[4];
  const float* Wout = (const float*)d_in[5];
  const float* bout = (const float*)d_in[6];
  float* out = (float*)d_out;

  const int B = in_sizes[0] / (TSEQ * DIN);   // 4096
  rnn_fused<<<dim3(B / 4), dim3(256), 0, stream>>>(x, Wih, Whh, bih, bhh, Wout, bout, out);
}